// Round 11
// baseline (397.853 us; speedup 1.0000x reference)
//
#include <hip/hip_runtime.h>
#include <hip/hip_bf16.h>

#define DIM 2048
#define SEQ 2048
#define NH 32
#define HD 64
#define NKV 8
#define QKV_LD 3072

typedef __attribute__((ext_vector_type(8))) short bf16x8;
typedef __attribute__((ext_vector_type(4))) float f32x4;
typedef __attribute__((ext_vector_type(2))) unsigned int uint2v;
typedef unsigned short ushort_t;

__device__ inline unsigned short f2bf(float f) {
    union { float f; unsigned int u; } v; v.f = f;
    unsigned int r = v.u + 0x7fffu + ((v.u >> 16) & 1u);
    return (unsigned short)(r >> 16);
}
__device__ inline float bf2f(ushort_t u) {
    union { unsigned int u; float f; } v; v.u = ((unsigned int)u) << 16; return v.f;
}

// async global->LDS, 16B per lane. LDS dest is wave-uniform base + lane*16.
__device__ inline void async_cp16(const void* g, void* l) {
    __builtin_amdgcn_global_load_lds(
        (const __attribute__((address_space(1))) unsigned int*)g,
        (__attribute__((address_space(3))) unsigned int*)l, 16, 0, 0);
}

// --- gfx950 register-only lane exchange (compiler builtins, hazard-safe) ----
__device__ inline void pswap32(unsigned int& a, unsigned int& b) {
    uint2v r = __builtin_amdgcn_permlane32_swap(a, b, false, false);
    a = r[0]; b = r[1];
}
__device__ inline void pswap16(unsigned int& a, unsigned int& b) {
    uint2v r = __builtin_amdgcn_permlane16_swap(a, b, false, false);
    a = r[0]; b = r[1];
}
// Wave reductions via swaps. The two outputs are {self, partner} per lane
// (in some order), so combining BOTH is direction-independent.
__device__ inline float wave_max(float x) {
    unsigned int a = __float_as_uint(x), b = a;
    uint2v r = __builtin_amdgcn_permlane16_swap(a, b, false, false);
    x = fmaxf(__uint_as_float(r[0]), __uint_as_float(r[1]));
    a = __float_as_uint(x); b = a;
    r = __builtin_amdgcn_permlane32_swap(a, b, false, false);
    return fmaxf(__uint_as_float(r[0]), __uint_as_float(r[1]));
}
__device__ inline float wave_sum(float x) {
    unsigned int a = __float_as_uint(x), b = a;
    uint2v r = __builtin_amdgcn_permlane16_swap(a, b, false, false);
    x = __uint_as_float(r[0]) + __uint_as_float(r[1]);
    a = __float_as_uint(x); b = a;
    r = __builtin_amdgcn_permlane32_swap(a, b, false, false);
    return __uint_as_float(r[0]) + __uint_as_float(r[1]);
}
__device__ inline unsigned int cvt_pk_bf16(float lo, float hi) {
    unsigned int r;
    asm volatile("v_cvt_pk_bf16_f32 %0, %1, %2" : "=v"(r) : "v"(lo), "v"(hi));
    return r;
}

// ---------------------------------------------------------------------------
// x fp32 -> bf16 (4 elems/thread)
// ---------------------------------------------------------------------------
__global__ __launch_bounds__(256) void convert_kernel(
    const float* __restrict__ X, ushort_t* __restrict__ Xb)
{
    int i = (blockIdx.x * 256 + threadIdx.x) * 4;
    float4 v = *(const float4*)(X + i);
    ushort_t o[4] = { f2bf(v.x), f2bf(v.y), f2bf(v.z), f2bf(v.w) };
    *(uint2*)(Xb + i) = *(uint2*)o;
}

// ---------------------------------------------------------------------------
// W fp32 [2048][N] -> WT bf16 [N][2048] (transpose + convert), 64x64 tiles.
// ---------------------------------------------------------------------------
__global__ __launch_bounds__(256) void transpose_kernel(
    const float* __restrict__ W, ushort_t* __restrict__ WT, int N)
{
    __shared__ __align__(16) ushort_t tile[64][72];
    const int n0 = blockIdx.x * 64, k0 = blockIdx.y * 64;
    const int t = threadIdx.x;
    {
        const int tk = t >> 4;
        const int tn = (t & 15) * 4;
        #pragma unroll
        for (int i = 0; i < 4; i++) {
            const int k = tk + i * 16;
            float4 v = *(const float4*)(W + (size_t)(k0 + k) * N + n0 + tn);
            tile[tn + 0][k] = f2bf(v.x);
            tile[tn + 1][k] = f2bf(v.y);
            tile[tn + 2][k] = f2bf(v.z);
            tile[tn + 3][k] = f2bf(v.w);
        }
    }
    __syncthreads();
    {
        const int tn = t >> 2;
        const int tk = (t & 3) * 16;
        uint4 a = *(const uint4*)&tile[tn][tk];
        uint4 b = *(const uint4*)&tile[tn][tk + 8];
        ushort_t* dst = WT + (size_t)(n0 + tn) * DIM + k0 + tk;
        *(uint4*)dst = a;
        *(uint4*)(dst + 8) = b;
    }
}

// ---------------------------------------------------------------------------
// GEMM: C[M,N] = A[M,K](bf16) * BT[N,K](bf16)^T.
// Tile 128(M) x 64(N), 256 threads, BK=32, global_load_lds staging.
//   QKV: grid 48x16 = 768 blocks = exactly 3/CU
//   O:   grid 32x16 = 512 blocks = exactly 2/CU
// ---------------------------------------------------------------------------
template<int OUT_F32>
__global__ __launch_bounds__(256) void gemm_kernel(
    const ushort_t* __restrict__ A, const ushort_t* __restrict__ BT,
    void* __restrict__ Cout, int K, int lda, int ldo)
{
    __shared__ __align__(16) ushort_t sA[128 * 32];
    __shared__ __align__(16) ushort_t sB[64 * 32];
    const int tn = blockIdx.x * 64, tm = blockIdx.y * 128;
    const int t = threadIdx.x, wave = t >> 6, lane = t & 63;
    const int m16 = lane & 15, quad = lane >> 4;
    const int wr = (wave >> 1) * 64, wc = (wave & 1) * 32;
    const int srow = lane >> 2;
    const int sce = (lane & 3) * 8;

    f32x4 acc[4][2] = {};

    for (int k0 = 0; k0 < K; k0 += 32) {
        __syncthreads();
        #pragma unroll
        for (int p = 0; p < 2; p++) {
            const int j = wave * 2 + p;
            const int row = j * 16 + srow;
            async_cp16(A + (size_t)(tm + row) * lda + k0 + sce, &sA[j * 512]);
        }
        async_cp16(BT + (size_t)(tn + wave * 16 + srow) * K + k0 + sce, &sB[wave * 512]);
        __syncthreads();
        bf16x8 af[4], bf[2];
        #pragma unroll
        for (int mt = 0; mt < 4; mt++)
            af[mt] = *(const bf16x8*)&sA[(wr + mt * 16 + m16) * 32 + quad * 8];
        #pragma unroll
        for (int nt = 0; nt < 2; nt++)
            bf[nt] = *(const bf16x8*)&sB[(wc + nt * 16 + m16) * 32 + quad * 8];
        #pragma unroll
        for (int mt = 0; mt < 4; mt++)
            #pragma unroll
            for (int nt = 0; nt < 2; nt++)
                acc[mt][nt] = __builtin_amdgcn_mfma_f32_16x16x32_bf16(af[mt], bf[nt], acc[mt][nt], 0, 0, 0);
    }

    #pragma unroll
    for (int mt = 0; mt < 4; mt++) {
        const int row = tm + wr + mt * 16 + quad * 4;
        #pragma unroll
        for (int nt = 0; nt < 2; nt++) {
            const int col = tn + wc + nt * 16 + m16;
            #pragma unroll
            for (int r = 0; r < 4; r++) {
                if (OUT_F32)
                    ((float*)Cout)[(size_t)(row + r) * ldo + col] = acc[mt][nt][r];
                else
                    ((ushort_t*)Cout)[(size_t)(row + r) * ldo + col] = f2bf(acc[mt][nt][r]);
            }
        }
    }
}

// ---------------------------------------------------------------------------
// RoPE, lane-per-element: one wave per 64-elem head slice, 1 shuffle/lane.
// Q pre-scaled by 0.125*log2(e) (exp2-domain attention scores).
// HW trig: angle in revolutions, fract + v_sin/v_cos. Error ~2e-4,
// well inside bf16 quantization.
// ---------------------------------------------------------------------------
#define QSCALE 0.18033688011112042f   // 0.125 * log2(e)
__global__ __launch_bounds__(256) void rope_kernel(ushort_t* qkv, ushort_t* __restrict__ Kr)
{
    const int gid = blockIdx.x * 256 + threadIdx.x;
    const int lane = gid & 63;
    const int idx = gid >> 6;              // slice index
    const int s = idx / 40;
    const int hh = idx - s * 40;

    const ushort_t* src;
    ushort_t* dst;
    const bool isq = (hh < 32);
    if (isq) {
        dst = qkv + (size_t)s * QKV_LD + hh * 64;
        src = dst;
    } else {
        src = qkv + (size_t)s * QKV_LD + 2048 + (hh - 32) * 64;
        dst = Kr + ((size_t)(hh - 32) * SEQ + s) * 64;
    }

    const float e = bf2f(src[lane]);
    const int i = lane & 31;
    // freq/(2*pi) = exp2(-i*log2(10000)/32) * (1/2pi)
    const float freq_rev = __builtin_amdgcn_exp2f(-(float)i * 0.4152410118609203f)
                           * 0.15915494309189535f;
    float fr = (float)s * freq_rev;
    fr = fr - floorf(fr);                  // v_fract range reduction
    const float cv = __builtin_amdgcn_cosf(fr);   // cos(fr * 2pi)
    const float sv = __builtin_amdgcn_sinf(fr);   // sin(fr * 2pi)
    const int partner = (lane < 32) ? (2 * lane + 1) : (2 * (lane - 32));
    const float y = __shfl(e, partner, 64);
    float out = (lane < 32) ? (e * cv - y * sv) : (e * cv + y * sv);
    if (isq) out *= QSCALE;
    dst[lane] = f2bf(out);
}

// ---------------------------------------------------------------------------
// V transpose (tiled through LDS): Vt[kvh][d][s] = qkv[s][2560+kvh*64+d]
// ---------------------------------------------------------------------------
__global__ __launch_bounds__(256) void vtrans_kernel(
    const ushort_t* __restrict__ qkv, ushort_t* __restrict__ Vt)
{
    __shared__ __align__(16) ushort_t tile[64][72];
    const int kvh = blockIdx.x & 7;
    const int s0 = (blockIdx.x >> 3) * 64;
    const int t = threadIdx.x;
    {
        const int sr = t >> 3;
        const int d8 = (t & 7) * 8;
        #pragma unroll
        for (int i = 0; i < 2; i++) {
            const int s = sr + i * 32;
            ushort_t tmp[8];
            *(uint4*)tmp = *(const uint4*)(qkv + (size_t)(s0 + s) * QKV_LD + 2560 + kvh * 64 + d8);
            #pragma unroll
            for (int j = 0; j < 8; j++) tile[d8 + j][s] = tmp[j];
        }
    }
    __syncthreads();
    {
        const int dr = t >> 3;
        const int s8 = (t & 7) * 8;
        #pragma unroll
        for (int i = 0; i < 2; i++) {
            const int d = dr + i * 32;
            *(uint4*)(Vt + ((size_t)kvh * 64 + d) * SEQ + s0 + s8) = *(const uint4*)&tile[d][s8];
        }
    }
}

// ---------------------------------------------------------------------------
// Flash attention R11 = R10 with the strip-decode fix.
// INVARIANT (required by the mask schedule): qa=0 queries lie in the band's
// LOWER 64 rows (strips 0-3: masked at k-tile nkt-2, skip nkt-1), qa=1 in
// the UPPER 64 (strips 4-7: masked at nkt-1). R10 violated it for v=1
// (strip = (wave&1)+qa*2+v*4 put qa=0 in strips 4-5) -> absmax 0.825.
// Fix: strip-within-half s4 = (wave&1) + v*2; strip = s4 + qa*4.
// Block = 256 threads (4 waves): waves 0-1 heavy band (15-p), waves 2-3
// light band (p); per-block work = 68 wave-tiles for EVERY block.
// Grid 512 = 2 blocks/CU; VGPR 116 <= 128 -> 4 waves/SIMD (2x R9 TLP).
// kvh = b&7 keeps one-kv-head-per-XCD L2 pinning.
// ---------------------------------------------------------------------------
#define MFMA16(A, B, C) __builtin_amdgcn_mfma_f32_16x16x32_bf16(A, B, C, 0, 0, 0)

#define LOADK(KF, KB) do { \
    _Pragma("unroll") \
    for (int _k = 0; _k < 4; _k++) { \
        const ushort_t* _kp = Krh + (size_t)((KB) + _k * 16 + m16) * 64 + quad * 8; \
        KF[_k][0] = *(const bf16x8*)_kp; \
        KF[_k][1] = *(const bf16x8*)(_kp + 32); \
    } \
} while (0)

#define LOADV(VF, KB) do { \
    _Pragma("unroll") \
    for (int _n = 0; _n < 4; _n++) { \
        const ushort_t* _vp = Vth + (size_t)(_n * 16 + m16) * SEQ + (KB) + quad * 8; \
        VF[_n][0] = *(const bf16x8*)_vp; \
        VF[_n][1] = *(const bf16x8*)(_vp + 32); \
    } \
} while (0)

#define QKT(SC, KF, QA) do { \
    _Pragma("unroll") \
    for (int _k = 0; _k < 4; _k++) { \
        SC[_k] = MFMA16(KF[_k][0], qf[QA][0], SC[_k]); \
        SC[_k] = MFMA16(KF[_k][1], qf[QA][1], SC[_k]); \
    } \
} while (0)

#define SMPV(SC, QA, DOMASK, KBASE, VF) do { \
    float s_[16]; \
    _Pragma("unroll") \
    for (int _k = 0; _k < 4; _k++) { \
        _Pragma("unroll") \
        for (int _r = 0; _r < 4; _r++) { \
            float _v = SC[_k][_r]; \
            if ((DOMASK) && ((KBASE) + _k * 16 + quad * 4 + _r > qi[QA])) _v = -1e30f; \
            s_[_k * 4 + _r] = _v; \
        } \
    } \
    float _x0 = fmaxf(s_[0], s_[1]),   _x1 = fmaxf(s_[2], s_[3]); \
    float _x2 = fmaxf(s_[4], s_[5]),   _x3 = fmaxf(s_[6], s_[7]); \
    float _x4 = fmaxf(s_[8], s_[9]),   _x5 = fmaxf(s_[10], s_[11]); \
    float _x6 = fmaxf(s_[12], s_[13]), _x7 = fmaxf(s_[14], s_[15]); \
    float _rmax = fmaxf(fmaxf(fmaxf(_x0, _x1), fmaxf(_x2, _x3)), \
                        fmaxf(fmaxf(_x4, _x5), fmaxf(_x6, _x7))); \
    _rmax = wave_max(_rmax); \
    if (_rmax > m_run[QA] + 8.f) { \
        const float _mnew = fmaxf(m_run[QA], _rmax); \
        const float _alpha = __builtin_amdgcn_exp2f(m_run[QA] - _mnew); \
        m_run[QA] = _mnew; \
        l_run[QA] *= _alpha; \
        _Pragma("unroll") \
        for (int _n = 0; _n < 4; _n++) { \
            _Pragma("unroll") \
            for (int _r = 0; _r < 4; _r++) oacc[QA][_n][_r] *= _alpha; \
        } \
    } \
    const float _m = m_run[QA]; \
    _Pragma("unroll") \
    for (int _i = 0; _i < 16; _i++) s_[_i] = __builtin_amdgcn_exp2f(s_[_i] - _m); \
    float _y0 = s_[0] + s_[1],   _y1 = s_[2] + s_[3]; \
    float _y2 = s_[4] + s_[5],   _y3 = s_[6] + s_[7]; \
    float _y4 = s_[8] + s_[9],   _y5 = s_[10] + s_[11]; \
    float _y6 = s_[12] + s_[13], _y7 = s_[14] + s_[15]; \
    float _ps = ((_y0 + _y1) + (_y2 + _y3)) + ((_y4 + _y5) + (_y6 + _y7)); \
    l_run[QA] += wave_sum(_ps); \
    unsigned int _u00 = cvt_pk_bf16(s_[0],  s_[1]),  _u01 = cvt_pk_bf16(s_[2],  s_[3]); \
    unsigned int _u10 = cvt_pk_bf16(s_[4],  s_[5]),  _u11 = cvt_pk_bf16(s_[6],  s_[7]); \
    unsigned int _u20 = cvt_pk_bf16(s_[8],  s_[9]),  _u21 = cvt_pk_bf16(s_[10], s_[11]); \
    unsigned int _u30 = cvt_pk_bf16(s_[12], s_[13]), _u31 = cvt_pk_bf16(s_[14], s_[15]); \
    pswap32(_u00, _u10); pswap16(_u00, _u10); \
    pswap32(_u01, _u11); pswap16(_u01, _u11); \
    pswap32(_u20, _u30); pswap16(_u20, _u30); \
    pswap32(_u21, _u31); pswap16(_u21, _u31); \
    union { unsigned int w[4]; bf16x8 v; } _P0, _P1; \
    _P0.w[0] = _u00; _P0.w[1] = _u01; _P0.w[2] = _u10; _P0.w[3] = _u11; \
    _P1.w[0] = _u20; _P1.w[1] = _u21; _P1.w[2] = _u30; _P1.w[3] = _u31; \
    __builtin_amdgcn_s_setprio(1); \
    _Pragma("unroll") \
    for (int _n = 0; _n < 4; _n++) { \
        oacc[QA][_n] = MFMA16(VF[_n][0], _P0.v, oacc[QA][_n]); \
        oacc[QA][_n] = MFMA16(VF[_n][1], _P1.v, oacc[QA][_n]); \
    } \
    __builtin_amdgcn_s_setprio(0); \
} while (0)

__global__ __launch_bounds__(256, 4) void attn_kernel(
    ushort_t* qkv, const ushort_t* __restrict__ Kr, const ushort_t* __restrict__ Vt)
{
    const int t = threadIdx.x, wave = t >> 6, lane = t & 63;
    const int m16 = lane & 15, quad = lane >> 4;
    // Decode: kvh = b&7 (XCD pin); head-in-group; pair p; strip-half v.
    const int b = blockIdx.x;
    const int kvh = b & 7;
    const int h = kvh * 4 + ((b >> 3) & 3);
    const int p = (b >> 5) & 7;                // pair index 0..7
    const int v = b >> 8;                      // strip-half 0..1
    const int grp = wave >> 1;                 // 0: heavy band, 1: light band
    const int band = grp ? p : 15 - p;         // 128-query band

    const ushort_t* Krh = Kr + (size_t)kvh * SEQ * 64;   // [s][d]
    const ushort_t* Vth = Vt + (size_t)kvh * 64 * SEQ;   // [d][s]

    const int nkt = band * 2 + 2;              // always even

    // Strip-within-half s4 = (wave&1) + v*2 (0..3); strip = s4 + qa*4.
    // Preserves the invariant: qa=0 -> lower 64 of band, qa=1 -> upper 64.
    const int s4 = (wave & 1) + v * 2;
    int qi[2];
    bf16x8 qf[2][2];
    #pragma unroll
    for (int qa = 0; qa < 2; qa++) {
        qi[qa] = band * 128 + (s4 + qa * 4) * 16 + m16;
        const ushort_t* qp = qkv + (size_t)qi[qa] * QKV_LD + h * 64 + quad * 8;
        qf[qa][0] = *(const bf16x8*)qp;
        qf[qa][1] = *(const bf16x8*)(qp + 32);
    }

    f32x4 oacc[2][4] = {};                  // O^T: col=q(m16), row=d
    float m_run[2] = { -1e30f, -1e30f };
    float l_run[2] = { 0.f, 0.f };

    bf16x8 kfA[4][2], kfB[4][2], vf[4][2];
    LOADK(kfA, 0);                          // prologue (pays latency once)

    for (int kt = 0; kt < nkt; kt += 2) {
        const bool lastpair = (kt == nkt - 2);
        const int kb0 = kt * 64, kb1 = kb0 + 64;

        // ---- even tile kt (buffers kfA) ----
        f32x4 scA0[4] = {}, scA1[4] = {};
        __builtin_amdgcn_s_setprio(1);
        QKT(scA0, kfA, 0);
        QKT(scA1, kfA, 1);
        __builtin_amdgcn_s_setprio(0);
        LOADV(vf, kb0);                     // consumed after softmax (~230cy)
        LOADK(kfB, kb1);                    // consumed next phase (~600cy)
        SMPV(scA0, 0, lastpair, kb0, vf);   // qa0 masks at tile nkt-2
        SMPV(scA1, 1, false,    kb0, vf);

        // ---- odd tile kt+1 (buffers kfB) ----
        if (!lastpair) {
            f32x4 scB0[4] = {}, scB1[4] = {};
            __builtin_amdgcn_s_setprio(1);
            QKT(scB0, kfB, 0);
            QKT(scB1, kfB, 1);
            __builtin_amdgcn_s_setprio(0);
            LOADV(vf, kb1);
            LOADK(kfA, kb1 + 64);
            SMPV(scB0, 0, false, kb1, vf);
            SMPV(scB1, 1, false, kb1, vf);
        } else {
            // final tile: fully masked for qa0 (skip); qa1 masked
            f32x4 scB1[4] = {};
            __builtin_amdgcn_s_setprio(1);
            QKT(scB1, kfB, 1);
            __builtin_amdgcn_s_setprio(0);
            LOADV(vf, kb1);
            SMPV(scB1, 1, true, kb1, vf);
        }
    }

    // ---- epilogue: O[q][h*64+d] = O^T/l ----
    #pragma unroll
    for (int qa = 0; qa < 2; qa++) {
        const float rl = 1.f / l_run[qa];
        #pragma unroll
        for (int nt = 0; nt < 4; nt++) {
            ushort_t pk[4];
            #pragma unroll
            for (int r = 0; r < 4; r++) pk[r] = f2bf(oacc[qa][nt][r] * rl);
            *(uint2*)&qkv[(size_t)qi[qa] * QKV_LD + h * 64 + nt * 16 + quad * 4] = *(uint2*)pk;
        }
    }
}

// ---------------------------------------------------------------------------
extern "C" void kernel_launch(void* const* d_in, const int* in_sizes, int n_in,
                              void* d_out, int out_size, void* d_ws, size_t ws_size,
                              hipStream_t stream)
{
    const float* x  = (const float*)d_in[0];
    // d_in[1] = mask (int32) — causal, handled analytically
    const float* wq = (const float*)d_in[2];
    const float* wk = (const float*)d_in[3];
    const float* wv = (const float*)d_in[4];
    const float* wo = (const float*)d_in[5];

    ushort_t* WT  = (ushort_t*)d_ws;                    // [3072][2048] bf16
    ushort_t* xb  = WT + (size_t)3072 * 2048;           // [2048][2048] bf16
    ushort_t* woT = xb;                                 // alias: xb dead after QKV GEMM
    ushort_t* qkv = xb + (size_t)2048 * 2048;           // [2048][3072] bf16
    ushort_t* Kr  = qkv + (size_t)SEQ * QKV_LD;         // [8][2048][64]
    ushort_t* Vt  = Kr + (size_t)NKV * SEQ * HD;        // [8][64][2048]

    dim3 blk(256);

    convert_kernel<<<(DIM * SEQ) / 1024, blk, 0, stream>>>(x, xb);
    transpose_kernel<<<dim3(32, 32), blk, 0, stream>>>(wq, WT, 2048);
    transpose_kernel<<<dim3(8, 32),  blk, 0, stream>>>(wk, WT + (size_t)2048 * 2048, 512);
    transpose_kernel<<<dim3(8, 32),  blk, 0, stream>>>(wv, WT + (size_t)2560 * 2048, 512);

    // Fused QKV projection: [2048,2048] x [2048,3072] -> qkv (128x64 tiles)
    gemm_kernel<0><<<dim3(QKV_LD / 64, SEQ / 128), blk, 0, stream>>>(xb, WT, qkv, DIM, DIM, QKV_LD);

    // wo transpose (reuses xb region — must follow the QKV GEMM)
    transpose_kernel<<<dim3(32, 32), blk, 0, stream>>>(wo, woT, 2048);

    // RoPE: SEQ*40 slices, one wave each (Q pre-scaled to exp2 domain)
    rope_kernel<<<(SEQ * 40 * 64) / 256, blk, 0, stream>>>(qkv, Kr);
    vtrans_kernel<<<NKV * (SEQ / 64), blk, 0, stream>>>(qkv, Vt);

    // Attention: 2 strip-halves x 8 pairs x 32 heads = 512 blocks (2/CU),
    // 4 waves each -> 4 waves/SIMD.
    attn_kernel<<<2 * 8 * NH, dim3(256), 0, stream>>>(qkv, Kr, Vt);

    // Output projection -> d_out fp32 (128x64 tiles, 512 blocks = 2/CU)
    gemm_kernel<1><<<dim3(DIM / 64, SEQ / 128), blk, 0, stream>>>(qkv, woT, d_out, DIM, QKV_LD, DIM);
}

// Round 12
// 297.099 us; speedup vs baseline: 1.3391x; 1.3391x over previous
//
#include <hip/hip_runtime.h>
#include <hip/hip_bf16.h>

#define DIM 2048
#define SEQ 2048
#define NH 32
#define HD 64
#define NKV 8
#define QKV_LD 3072

typedef __attribute__((ext_vector_type(8))) short bf16x8;
typedef __attribute__((ext_vector_type(4))) float f32x4;
typedef __attribute__((ext_vector_type(2))) unsigned int uint2v;
typedef unsigned short ushort_t;

__device__ inline unsigned short f2bf(float f) {
    union { float f; unsigned int u; } v; v.f = f;
    unsigned int r = v.u + 0x7fffu + ((v.u >> 16) & 1u);
    return (unsigned short)(r >> 16);
}
__device__ inline float bf2f(ushort_t u) {
    union { unsigned int u; float f; } v; v.u = ((unsigned int)u) << 16; return v.f;
}

// async global->LDS, 16B per lane. LDS dest is wave-uniform base + lane*16.
__device__ inline void async_cp16(const void* g, void* l) {
    __builtin_amdgcn_global_load_lds(
        (const __attribute__((address_space(1))) unsigned int*)g,
        (__attribute__((address_space(3))) unsigned int*)l, 16, 0, 0);
}

// --- gfx950 register-only lane exchange (compiler builtins, hazard-safe) ----
__device__ inline void pswap32(unsigned int& a, unsigned int& b) {
    uint2v r = __builtin_amdgcn_permlane32_swap(a, b, false, false);
    a = r[0]; b = r[1];
}
__device__ inline void pswap16(unsigned int& a, unsigned int& b) {
    uint2v r = __builtin_amdgcn_permlane16_swap(a, b, false, false);
    a = r[0]; b = r[1];
}
// Wave reductions via swaps. The two outputs are {self, partner} per lane
// (in some order), so combining BOTH is direction-independent.
__device__ inline float wave_max(float x) {
    unsigned int a = __float_as_uint(x), b = a;
    uint2v r = __builtin_amdgcn_permlane16_swap(a, b, false, false);
    x = fmaxf(__uint_as_float(r[0]), __uint_as_float(r[1]));
    a = __float_as_uint(x); b = a;
    r = __builtin_amdgcn_permlane32_swap(a, b, false, false);
    return fmaxf(__uint_as_float(r[0]), __uint_as_float(r[1]));
}
__device__ inline float wave_sum(float x) {
    unsigned int a = __float_as_uint(x), b = a;
    uint2v r = __builtin_amdgcn_permlane16_swap(a, b, false, false);
    x = __uint_as_float(r[0]) + __uint_as_float(r[1]);
    a = __float_as_uint(x); b = a;
    r = __builtin_amdgcn_permlane32_swap(a, b, false, false);
    return __uint_as_float(r[0]) + __uint_as_float(r[1]);
}
__device__ inline unsigned int cvt_pk_bf16(float lo, float hi) {
    unsigned int r;
    asm volatile("v_cvt_pk_bf16_f32 %0, %1, %2" : "=v"(r) : "v"(lo), "v"(hi));
    return r;
}

// ---------------------------------------------------------------------------
// x fp32 -> bf16 (4 elems/thread)
// ---------------------------------------------------------------------------
__global__ __launch_bounds__(256) void convert_kernel(
    const float* __restrict__ X, ushort_t* __restrict__ Xb)
{
    int i = (blockIdx.x * 256 + threadIdx.x) * 4;
    float4 v = *(const float4*)(X + i);
    ushort_t o[4] = { f2bf(v.x), f2bf(v.y), f2bf(v.z), f2bf(v.w) };
    *(uint2*)(Xb + i) = *(uint2*)o;
}

// ---------------------------------------------------------------------------
// W fp32 [2048][N] -> WT bf16 [N][2048] (transpose + convert), 64x64 tiles.
// ---------------------------------------------------------------------------
__global__ __launch_bounds__(256) void transpose_kernel(
    const float* __restrict__ W, ushort_t* __restrict__ WT, int N)
{
    __shared__ __align__(16) ushort_t tile[64][72];
    const int n0 = blockIdx.x * 64, k0 = blockIdx.y * 64;
    const int t = threadIdx.x;
    {
        const int tk = t >> 4;
        const int tn = (t & 15) * 4;
        #pragma unroll
        for (int i = 0; i < 4; i++) {
            const int k = tk + i * 16;
            float4 v = *(const float4*)(W + (size_t)(k0 + k) * N + n0 + tn);
            tile[tn + 0][k] = f2bf(v.x);
            tile[tn + 1][k] = f2bf(v.y);
            tile[tn + 2][k] = f2bf(v.z);
            tile[tn + 3][k] = f2bf(v.w);
        }
    }
    __syncthreads();
    {
        const int tn = t >> 2;
        const int tk = (t & 3) * 16;
        uint4 a = *(const uint4*)&tile[tn][tk];
        uint4 b = *(const uint4*)&tile[tn][tk + 8];
        ushort_t* dst = WT + (size_t)(n0 + tn) * DIM + k0 + tk;
        *(uint4*)dst = a;
        *(uint4*)(dst + 8) = b;
    }
}

// ---------------------------------------------------------------------------
// GEMM: C[M,N] = A[M,K](bf16) * BT[N,K](bf16)^T.
// Tile 128(M) x 64(N), 256 threads, BK=32, global_load_lds staging.
//   QKV: grid 48x16 = 768 blocks = exactly 3/CU
//   O:   grid 32x16 = 512 blocks = exactly 2/CU
// ---------------------------------------------------------------------------
template<int OUT_F32>
__global__ __launch_bounds__(256) void gemm_kernel(
    const ushort_t* __restrict__ A, const ushort_t* __restrict__ BT,
    void* __restrict__ Cout, int K, int lda, int ldo)
{
    __shared__ __align__(16) ushort_t sA[128 * 32];
    __shared__ __align__(16) ushort_t sB[64 * 32];
    const int tn = blockIdx.x * 64, tm = blockIdx.y * 128;
    const int t = threadIdx.x, wave = t >> 6, lane = t & 63;
    const int m16 = lane & 15, quad = lane >> 4;
    const int wr = (wave >> 1) * 64, wc = (wave & 1) * 32;
    const int srow = lane >> 2;
    const int sce = (lane & 3) * 8;

    f32x4 acc[4][2] = {};

    for (int k0 = 0; k0 < K; k0 += 32) {
        __syncthreads();
        #pragma unroll
        for (int p = 0; p < 2; p++) {
            const int j = wave * 2 + p;
            const int row = j * 16 + srow;
            async_cp16(A + (size_t)(tm + row) * lda + k0 + sce, &sA[j * 512]);
        }
        async_cp16(BT + (size_t)(tn + wave * 16 + srow) * K + k0 + sce, &sB[wave * 512]);
        __syncthreads();
        bf16x8 af[4], bf[2];
        #pragma unroll
        for (int mt = 0; mt < 4; mt++)
            af[mt] = *(const bf16x8*)&sA[(wr + mt * 16 + m16) * 32 + quad * 8];
        #pragma unroll
        for (int nt = 0; nt < 2; nt++)
            bf[nt] = *(const bf16x8*)&sB[(wc + nt * 16 + m16) * 32 + quad * 8];
        #pragma unroll
        for (int mt = 0; mt < 4; mt++)
            #pragma unroll
            for (int nt = 0; nt < 2; nt++)
                acc[mt][nt] = __builtin_amdgcn_mfma_f32_16x16x32_bf16(af[mt], bf[nt], acc[mt][nt], 0, 0, 0);
    }

    #pragma unroll
    for (int mt = 0; mt < 4; mt++) {
        const int row = tm + wr + mt * 16 + quad * 4;
        #pragma unroll
        for (int nt = 0; nt < 2; nt++) {
            const int col = tn + wc + nt * 16 + m16;
            #pragma unroll
            for (int r = 0; r < 4; r++) {
                if (OUT_F32)
                    ((float*)Cout)[(size_t)(row + r) * ldo + col] = acc[mt][nt][r];
                else
                    ((ushort_t*)Cout)[(size_t)(row + r) * ldo + col] = f2bf(acc[mt][nt][r]);
            }
        }
    }
}

// ---------------------------------------------------------------------------
// RoPE, lane-per-element: one wave per 64-elem head slice, 1 shuffle/lane.
// Q pre-scaled by 0.125*log2(e) (exp2-domain attention scores).
// HW trig: angle in revolutions, fract + v_sin/v_cos. Error ~2e-4,
// well inside bf16 quantization.
// ---------------------------------------------------------------------------
#define QSCALE 0.18033688011112042f   // 0.125 * log2(e)
__global__ __launch_bounds__(256) void rope_kernel(ushort_t* qkv, ushort_t* __restrict__ Kr)
{
    const int gid = blockIdx.x * 256 + threadIdx.x;
    const int lane = gid & 63;
    const int idx = gid >> 6;              // slice index
    const int s = idx / 40;
    const int hh = idx - s * 40;

    const ushort_t* src;
    ushort_t* dst;
    const bool isq = (hh < 32);
    if (isq) {
        dst = qkv + (size_t)s * QKV_LD + hh * 64;
        src = dst;
    } else {
        src = qkv + (size_t)s * QKV_LD + 2048 + (hh - 32) * 64;
        dst = Kr + ((size_t)(hh - 32) * SEQ + s) * 64;
    }

    const float e = bf2f(src[lane]);
    const int i = lane & 31;
    // freq/(2*pi) = exp2(-i*log2(10000)/32) * (1/2pi)
    const float freq_rev = __builtin_amdgcn_exp2f(-(float)i * 0.4152410118609203f)
                           * 0.15915494309189535f;
    float fr = (float)s * freq_rev;
    fr = fr - floorf(fr);                  // v_fract range reduction
    const float cv = __builtin_amdgcn_cosf(fr);   // cos(fr * 2pi)
    const float sv = __builtin_amdgcn_sinf(fr);   // sin(fr * 2pi)
    const int partner = (lane < 32) ? (2 * lane + 1) : (2 * (lane - 32));
    const float y = __shfl(e, partner, 64);
    float out = (lane < 32) ? (e * cv - y * sv) : (e * cv + y * sv);
    if (isq) out *= QSCALE;
    dst[lane] = f2bf(out);
}

// ---------------------------------------------------------------------------
// V transpose (tiled through LDS): Vt[kvh][d][s] = qkv[s][2560+kvh*64+d]
// ---------------------------------------------------------------------------
__global__ __launch_bounds__(256) void vtrans_kernel(
    const ushort_t* __restrict__ qkv, ushort_t* __restrict__ Vt)
{
    __shared__ __align__(16) ushort_t tile[64][72];
    const int kvh = blockIdx.x & 7;
    const int s0 = (blockIdx.x >> 3) * 64;
    const int t = threadIdx.x;
    {
        const int sr = t >> 3;
        const int d8 = (t & 7) * 8;
        #pragma unroll
        for (int i = 0; i < 2; i++) {
            const int s = sr + i * 32;
            ushort_t tmp[8];
            *(uint4*)tmp = *(const uint4*)(qkv + (size_t)(s0 + s) * QKV_LD + 2560 + kvh * 64 + d8);
            #pragma unroll
            for (int j = 0; j < 8; j++) tile[d8 + j][s] = tmp[j];
        }
    }
    __syncthreads();
    {
        const int dr = t >> 3;
        const int s8 = (t & 7) * 8;
        #pragma unroll
        for (int i = 0; i < 2; i++) {
            const int d = dr + i * 32;
            *(uint4*)(Vt + ((size_t)kvh * 64 + d) * SEQ + s0 + s8) = *(const uint4*)&tile[d][s8];
        }
    }
}

// ---------------------------------------------------------------------------
// Flash attention R12 = R11 with the VGPR clamp removed.
// R11's launch_bounds(256,4) clamped the allocator to VGPR=64 (< the ~116
// this code needs) -> massive scratch spill (WRITE_SIZE 8 MB -> 321 MB,
// attn 69 -> 176 us). Spill scratch ops also increment vmcnt, which is what
// silently broke R7/R8's counted-vmcnt kernels. Fix: launch_bounds(256) —
// allocator free; code compiles to ~116 VGPR (R9 evidence, same per-wave
// code), and HW occupancy is then set by ACTUAL use: 116 <= 128 -> 4 blocks/
// CU = 4 waves/SIMD, the TLP target of this restructure.
// Block = 256 threads (4 waves): waves 0-1 heavy band (15-p), waves 2-3
// light band (p); strip-within-half s4 = (wave&1)+v*2, strip = s4+qa*4
// (qa=0 lower 64 of band, qa=1 upper — the mask-schedule invariant).
// Per-block work = 68 wave-tiles for EVERY block. Grid 512 = 2 blocks/CU.
// kvh = b&7 keeps one-kv-head-per-XCD L2 pinning.
// ---------------------------------------------------------------------------
#define MFMA16(A, B, C) __builtin_amdgcn_mfma_f32_16x16x32_bf16(A, B, C, 0, 0, 0)

#define LOADK(KF, KB) do { \
    _Pragma("unroll") \
    for (int _k = 0; _k < 4; _k++) { \
        const ushort_t* _kp = Krh + (size_t)((KB) + _k * 16 + m16) * 64 + quad * 8; \
        KF[_k][0] = *(const bf16x8*)_kp; \
        KF[_k][1] = *(const bf16x8*)(_kp + 32); \
    } \
} while (0)

#define LOADV(VF, KB) do { \
    _Pragma("unroll") \
    for (int _n = 0; _n < 4; _n++) { \
        const ushort_t* _vp = Vth + (size_t)(_n * 16 + m16) * SEQ + (KB) + quad * 8; \
        VF[_n][0] = *(const bf16x8*)_vp; \
        VF[_n][1] = *(const bf16x8*)(_vp + 32); \
    } \
} while (0)

#define QKT(SC, KF, QA) do { \
    _Pragma("unroll") \
    for (int _k = 0; _k < 4; _k++) { \
        SC[_k] = MFMA16(KF[_k][0], qf[QA][0], SC[_k]); \
        SC[_k] = MFMA16(KF[_k][1], qf[QA][1], SC[_k]); \
    } \
} while (0)

#define SMPV(SC, QA, DOMASK, KBASE, VF) do { \
    float s_[16]; \
    _Pragma("unroll") \
    for (int _k = 0; _k < 4; _k++) { \
        _Pragma("unroll") \
        for (int _r = 0; _r < 4; _r++) { \
            float _v = SC[_k][_r]; \
            if ((DOMASK) && ((KBASE) + _k * 16 + quad * 4 + _r > qi[QA])) _v = -1e30f; \
            s_[_k * 4 + _r] = _v; \
        } \
    } \
    float _x0 = fmaxf(s_[0], s_[1]),   _x1 = fmaxf(s_[2], s_[3]); \
    float _x2 = fmaxf(s_[4], s_[5]),   _x3 = fmaxf(s_[6], s_[7]); \
    float _x4 = fmaxf(s_[8], s_[9]),   _x5 = fmaxf(s_[10], s_[11]); \
    float _x6 = fmaxf(s_[12], s_[13]), _x7 = fmaxf(s_[14], s_[15]); \
    float _rmax = fmaxf(fmaxf(fmaxf(_x0, _x1), fmaxf(_x2, _x3)), \
                        fmaxf(fmaxf(_x4, _x5), fmaxf(_x6, _x7))); \
    _rmax = wave_max(_rmax); \
    if (_rmax > m_run[QA] + 8.f) { \
        const float _mnew = fmaxf(m_run[QA], _rmax); \
        const float _alpha = __builtin_amdgcn_exp2f(m_run[QA] - _mnew); \
        m_run[QA] = _mnew; \
        l_run[QA] *= _alpha; \
        _Pragma("unroll") \
        for (int _n = 0; _n < 4; _n++) { \
            _Pragma("unroll") \
            for (int _r = 0; _r < 4; _r++) oacc[QA][_n][_r] *= _alpha; \
        } \
    } \
    const float _m = m_run[QA]; \
    _Pragma("unroll") \
    for (int _i = 0; _i < 16; _i++) s_[_i] = __builtin_amdgcn_exp2f(s_[_i] - _m); \
    float _y0 = s_[0] + s_[1],   _y1 = s_[2] + s_[3]; \
    float _y2 = s_[4] + s_[5],   _y3 = s_[6] + s_[7]; \
    float _y4 = s_[8] + s_[9],   _y5 = s_[10] + s_[11]; \
    float _y6 = s_[12] + s_[13], _y7 = s_[14] + s_[15]; \
    float _ps = ((_y0 + _y1) + (_y2 + _y3)) + ((_y4 + _y5) + (_y6 + _y7)); \
    l_run[QA] += wave_sum(_ps); \
    unsigned int _u00 = cvt_pk_bf16(s_[0],  s_[1]),  _u01 = cvt_pk_bf16(s_[2],  s_[3]); \
    unsigned int _u10 = cvt_pk_bf16(s_[4],  s_[5]),  _u11 = cvt_pk_bf16(s_[6],  s_[7]); \
    unsigned int _u20 = cvt_pk_bf16(s_[8],  s_[9]),  _u21 = cvt_pk_bf16(s_[10], s_[11]); \
    unsigned int _u30 = cvt_pk_bf16(s_[12], s_[13]), _u31 = cvt_pk_bf16(s_[14], s_[15]); \
    pswap32(_u00, _u10); pswap16(_u00, _u10); \
    pswap32(_u01, _u11); pswap16(_u01, _u11); \
    pswap32(_u20, _u30); pswap16(_u20, _u30); \
    pswap32(_u21, _u31); pswap16(_u21, _u31); \
    union { unsigned int w[4]; bf16x8 v; } _P0, _P1; \
    _P0.w[0] = _u00; _P0.w[1] = _u01; _P0.w[2] = _u10; _P0.w[3] = _u11; \
    _P1.w[0] = _u20; _P1.w[1] = _u21; _P1.w[2] = _u30; _P1.w[3] = _u31; \
    __builtin_amdgcn_s_setprio(1); \
    _Pragma("unroll") \
    for (int _n = 0; _n < 4; _n++) { \
        oacc[QA][_n] = MFMA16(VF[_n][0], _P0.v, oacc[QA][_n]); \
        oacc[QA][_n] = MFMA16(VF[_n][1], _P1.v, oacc[QA][_n]); \
    } \
    __builtin_amdgcn_s_setprio(0); \
} while (0)

__global__ __launch_bounds__(256) void attn_kernel(
    ushort_t* qkv, const ushort_t* __restrict__ Kr, const ushort_t* __restrict__ Vt)
{
    const int t = threadIdx.x, wave = t >> 6, lane = t & 63;
    const int m16 = lane & 15, quad = lane >> 4;
    // Decode: kvh = b&7 (XCD pin); head-in-group; pair p; strip-half v.
    const int b = blockIdx.x;
    const int kvh = b & 7;
    const int h = kvh * 4 + ((b >> 3) & 3);
    const int p = (b >> 5) & 7;                // pair index 0..7
    const int v = b >> 8;                      // strip-half 0..1
    const int grp = wave >> 1;                 // 0: heavy band, 1: light band
    const int band = grp ? p : 15 - p;         // 128-query band

    const ushort_t* Krh = Kr + (size_t)kvh * SEQ * 64;   // [s][d]
    const ushort_t* Vth = Vt + (size_t)kvh * 64 * SEQ;   // [d][s]

    const int nkt = band * 2 + 2;              // always even

    // Strip-within-half s4 = (wave&1) + v*2 (0..3); strip = s4 + qa*4.
    // Preserves the invariant: qa=0 -> lower 64 of band, qa=1 -> upper 64.
    const int s4 = (wave & 1) + v * 2;
    int qi[2];
    bf16x8 qf[2][2];
    #pragma unroll
    for (int qa = 0; qa < 2; qa++) {
        qi[qa] = band * 128 + (s4 + qa * 4) * 16 + m16;
        const ushort_t* qp = qkv + (size_t)qi[qa] * QKV_LD + h * 64 + quad * 8;
        qf[qa][0] = *(const bf16x8*)qp;
        qf[qa][1] = *(const bf16x8*)(qp + 32);
    }

    f32x4 oacc[2][4] = {};                  // O^T: col=q(m16), row=d
    float m_run[2] = { -1e30f, -1e30f };
    float l_run[2] = { 0.f, 0.f };

    bf16x8 kfA[4][2], kfB[4][2], vf[4][2];
    LOADK(kfA, 0);                          // prologue (pays latency once)

    for (int kt = 0; kt < nkt; kt += 2) {
        const bool lastpair = (kt == nkt - 2);
        const int kb0 = kt * 64, kb1 = kb0 + 64;

        // ---- even tile kt (buffers kfA) ----
        f32x4 scA0[4] = {}, scA1[4] = {};
        __builtin_amdgcn_s_setprio(1);
        QKT(scA0, kfA, 0);
        QKT(scA1, kfA, 1);
        __builtin_amdgcn_s_setprio(0);
        LOADV(vf, kb0);                     // consumed after softmax (~230cy)
        LOADK(kfB, kb1);                    // consumed next phase (~600cy)
        SMPV(scA0, 0, lastpair, kb0, vf);   // qa0 masks at tile nkt-2
        SMPV(scA1, 1, false,    kb0, vf);

        // ---- odd tile kt+1 (buffers kfB) ----
        if (!lastpair) {
            f32x4 scB0[4] = {}, scB1[4] = {};
            __builtin_amdgcn_s_setprio(1);
            QKT(scB0, kfB, 0);
            QKT(scB1, kfB, 1);
            __builtin_amdgcn_s_setprio(0);
            LOADV(vf, kb1);
            LOADK(kfA, kb1 + 64);
            SMPV(scB0, 0, false, kb1, vf);
            SMPV(scB1, 1, false, kb1, vf);
        } else {
            // final tile: fully masked for qa0 (skip); qa1 masked
            f32x4 scB1[4] = {};
            __builtin_amdgcn_s_setprio(1);
            QKT(scB1, kfB, 1);
            __builtin_amdgcn_s_setprio(0);
            LOADV(vf, kb1);
            SMPV(scB1, 1, true, kb1, vf);
        }
    }

    // ---- epilogue: O[q][h*64+d] = O^T/l ----
    #pragma unroll
    for (int qa = 0; qa < 2; qa++) {
        const float rl = 1.f / l_run[qa];
        #pragma unroll
        for (int nt = 0; nt < 4; nt++) {
            ushort_t pk[4];
            #pragma unroll
            for (int r = 0; r < 4; r++) pk[r] = f2bf(oacc[qa][nt][r] * rl);
            *(uint2*)&qkv[(size_t)qi[qa] * QKV_LD + h * 64 + nt * 16 + quad * 4] = *(uint2*)pk;
        }
    }
}

// ---------------------------------------------------------------------------
extern "C" void kernel_launch(void* const* d_in, const int* in_sizes, int n_in,
                              void* d_out, int out_size, void* d_ws, size_t ws_size,
                              hipStream_t stream)
{
    const float* x  = (const float*)d_in[0];
    // d_in[1] = mask (int32) — causal, handled analytically
    const float* wq = (const float*)d_in[2];
    const float* wk = (const float*)d_in[3];
    const float* wv = (const float*)d_in[4];
    const float* wo = (const float*)d_in[5];

    ushort_t* WT  = (ushort_t*)d_ws;                    // [3072][2048] bf16
    ushort_t* xb  = WT + (size_t)3072 * 2048;           // [2048][2048] bf16
    ushort_t* woT = xb;                                 // alias: xb dead after QKV GEMM
    ushort_t* qkv = xb + (size_t)2048 * 2048;           // [2048][3072] bf16
    ushort_t* Kr  = qkv + (size_t)SEQ * QKV_LD;         // [8][2048][64]
    ushort_t* Vt  = Kr + (size_t)NKV * SEQ * HD;        // [8][64][2048]

    dim3 blk(256);

    convert_kernel<<<(DIM * SEQ) / 1024, blk, 0, stream>>>(x, xb);
    transpose_kernel<<<dim3(32, 32), blk, 0, stream>>>(wq, WT, 2048);
    transpose_kernel<<<dim3(8, 32),  blk, 0, stream>>>(wk, WT + (size_t)2048 * 2048, 512);
    transpose_kernel<<<dim3(8, 32),  blk, 0, stream>>>(wv, WT + (size_t)2560 * 2048, 512);

    // Fused QKV projection: [2048,2048] x [2048,3072] -> qkv (128x64 tiles)
    gemm_kernel<0><<<dim3(QKV_LD / 64, SEQ / 128), blk, 0, stream>>>(xb, WT, qkv, DIM, DIM, QKV_LD);

    // wo transpose (reuses xb region — must follow the QKV GEMM)
    transpose_kernel<<<dim3(32, 32), blk, 0, stream>>>(wo, woT, 2048);

    // RoPE: SEQ*40 slices, one wave each (Q pre-scaled to exp2 domain)
    rope_kernel<<<(SEQ * 40 * 64) / 256, blk, 0, stream>>>(qkv, Kr);
    vtrans_kernel<<<NKV * (SEQ / 64), blk, 0, stream>>>(qkv, Vt);

    // Attention: 2 strip-halves x 8 pairs x 32 heads = 512 blocks (2/CU),
    // 4 waves each; VGPR ~116 <= 128 -> HW allows 4 waves/SIMD.
    attn_kernel<<<2 * 8 * NH, dim3(256), 0, stream>>>(qkv, Kr, Vt);

    // Output projection -> d_out fp32 (128x64 tiles, 512 blocks = 2/CU)
    gemm_kernel<1><<<dim3(DIM / 64, SEQ / 128), blk, 0, stream>>>(qkv, woT, d_out, DIM, QKV_LD, DIM);
}

// Round 13
// 259.494 us; speedup vs baseline: 1.5332x; 1.1449x over previous
//
#include <hip/hip_runtime.h>
#include <hip/hip_bf16.h>

#define DIM 2048
#define SEQ 2048
#define NH 32
#define HD 64
#define NKV 8
#define QKV_LD 3072

typedef __attribute__((ext_vector_type(8))) short bf16x8;
typedef __attribute__((ext_vector_type(4))) float f32x4;
typedef __attribute__((ext_vector_type(2))) unsigned int uint2v;
typedef unsigned short ushort_t;

__device__ inline unsigned short f2bf(float f) {
    union { float f; unsigned int u; } v; v.f = f;
    unsigned int r = v.u + 0x7fffu + ((v.u >> 16) & 1u);
    return (unsigned short)(r >> 16);
}
__device__ inline float bf2f(ushort_t u) {
    union { unsigned int u; float f; } v; v.u = ((unsigned int)u) << 16; return v.f;
}

// async global->LDS, 16B per lane. LDS dest is wave-uniform base + lane*16.
__device__ inline void async_cp16(const void* g, void* l) {
    __builtin_amdgcn_global_load_lds(
        (const __attribute__((address_space(1))) unsigned int*)g,
        (__attribute__((address_space(3))) unsigned int*)l, 16, 0, 0);
}

// --- gfx950 register-only lane exchange (compiler builtins, hazard-safe) ----
__device__ inline void pswap32(unsigned int& a, unsigned int& b) {
    uint2v r = __builtin_amdgcn_permlane32_swap(a, b, false, false);
    a = r[0]; b = r[1];
}
__device__ inline void pswap16(unsigned int& a, unsigned int& b) {
    uint2v r = __builtin_amdgcn_permlane16_swap(a, b, false, false);
    a = r[0]; b = r[1];
}
// Wave reductions via swaps. The two outputs are {self, partner} per lane
// (in some order), so combining BOTH is direction-independent.
__device__ inline float wave_max(float x) {
    unsigned int a = __float_as_uint(x), b = a;
    uint2v r = __builtin_amdgcn_permlane16_swap(a, b, false, false);
    x = fmaxf(__uint_as_float(r[0]), __uint_as_float(r[1]));
    a = __float_as_uint(x); b = a;
    r = __builtin_amdgcn_permlane32_swap(a, b, false, false);
    return fmaxf(__uint_as_float(r[0]), __uint_as_float(r[1]));
}
__device__ inline float wave_sum(float x) {
    unsigned int a = __float_as_uint(x), b = a;
    uint2v r = __builtin_amdgcn_permlane16_swap(a, b, false, false);
    x = __uint_as_float(r[0]) + __uint_as_float(r[1]);
    a = __float_as_uint(x); b = a;
    r = __builtin_amdgcn_permlane32_swap(a, b, false, false);
    return __uint_as_float(r[0]) + __uint_as_float(r[1]);
}
__device__ inline unsigned int cvt_pk_bf16(float lo, float hi) {
    unsigned int r;
    asm volatile("v_cvt_pk_bf16_f32 %0, %1, %2" : "=v"(r) : "v"(lo), "v"(hi));
    return r;
}

// ---------------------------------------------------------------------------
// x fp32 -> bf16 (4 elems/thread)
// ---------------------------------------------------------------------------
__global__ __launch_bounds__(256) void convert_kernel(
    const float* __restrict__ X, ushort_t* __restrict__ Xb)
{
    int i = (blockIdx.x * 256 + threadIdx.x) * 4;
    float4 v = *(const float4*)(X + i);
    ushort_t o[4] = { f2bf(v.x), f2bf(v.y), f2bf(v.z), f2bf(v.w) };
    *(uint2*)(Xb + i) = *(uint2*)o;
}

// ---------------------------------------------------------------------------
// W fp32 [2048][N] -> WT bf16 [N][2048] (transpose + convert), 64x64 tiles.
// ---------------------------------------------------------------------------
__global__ __launch_bounds__(256) void transpose_kernel(
    const float* __restrict__ W, ushort_t* __restrict__ WT, int N)
{
    __shared__ __align__(16) ushort_t tile[64][72];
    const int n0 = blockIdx.x * 64, k0 = blockIdx.y * 64;
    const int t = threadIdx.x;
    {
        const int tk = t >> 4;
        const int tn = (t & 15) * 4;
        #pragma unroll
        for (int i = 0; i < 4; i++) {
            const int k = tk + i * 16;
            float4 v = *(const float4*)(W + (size_t)(k0 + k) * N + n0 + tn);
            tile[tn + 0][k] = f2bf(v.x);
            tile[tn + 1][k] = f2bf(v.y);
            tile[tn + 2][k] = f2bf(v.z);
            tile[tn + 3][k] = f2bf(v.w);
        }
    }
    __syncthreads();
    {
        const int tn = t >> 2;
        const int tk = (t & 3) * 16;
        uint4 a = *(const uint4*)&tile[tn][tk];
        uint4 b = *(const uint4*)&tile[tn][tk + 8];
        ushort_t* dst = WT + (size_t)(n0 + tn) * DIM + k0 + tk;
        *(uint4*)dst = a;
        *(uint4*)(dst + 8) = b;
    }
}

// ---------------------------------------------------------------------------
// GEMM R13: C[M,N] = A[M,K](bf16) * BT[N,K](bf16)^T.
// Tile 128(M) x 64(N), BK=64, 256 threads, DOUBLE-BUFFERED LDS with ONE
// barrier per K-step (min-2-phase, T3 recipe): next-tile GSTAGE is issued
// BEFORE the current tile's ds_read+MFMA, so its HBM/L2 latency hides under
// compute instead of being fully exposed between two barriers (the old
// structure's dominant cost at 1.5-3 blocks/CU).
// BK=64 rows are 128 B -> 16-way ds_read bank conflict if linear; fixed via
// the both-sides XOR swizzle (T2 / m201 / rule #21): LDS dest stays linear
// (global_load_lds requirement), SOURCE col-block = (lane&7)^srow, READ
// col-block = (kk*4+quad)^(row&7). Involution; 2-way conflicts (free).
// LDS 48 KB -> 3 blocks/CU. Grids: QKV 48x16=768 (3/CU), O 32x16=512 (2/CU).
// ---------------------------------------------------------------------------
template<int OUT_F32>
__global__ __launch_bounds__(256) void gemm_kernel(
    const ushort_t* __restrict__ A, const ushort_t* __restrict__ BT,
    void* __restrict__ Cout, int K, int lda, int ldo)
{
    __shared__ __align__(16) ushort_t sA[2][128 * 64];
    __shared__ __align__(16) ushort_t sB[2][64 * 64];
    const int tn = blockIdx.x * 64, tm = blockIdx.y * 128;
    const int t = threadIdx.x, wave = t >> 6, lane = t & 63;
    const int m16 = lane & 15, quad = lane >> 4;
    const int wr = (wave >> 1) * 64, wc = (wave & 1) * 32;
    const int srow = lane >> 3;                    // row within 8-row slab
    const int scol = ((lane & 7) ^ srow) * 8;      // XOR-preswizzled source col

    f32x4 acc[4][2] = {};
    const int nsteps = K >> 6;

#define GSTAGE(BUF, KO) do { \
    _Pragma("unroll") \
    for (int _p = 0; _p < 4; _p++) { \
        const int _j = wave * 4 + _p; \
        async_cp16(A + (size_t)(tm + _j * 8 + srow) * lda + (KO) + scol, &sA[BUF][_j * 512]); \
    } \
    _Pragma("unroll") \
    for (int _p = 0; _p < 2; _p++) { \
        const int _j = wave * 2 + _p; \
        async_cp16(BT + (size_t)(tn + _j * 8 + srow) * K + (KO) + scol, &sB[BUF][_j * 512]); \
    } \
} while (0)

    GSTAGE(0, 0);
    int cur = 0;
    for (int kt = 0; kt < nsteps; kt++) {
        __syncthreads();            // implicit vmcnt(0)+barrier: buf[cur] landed
        if (kt + 1 < nsteps) GSTAGE(cur ^ 1, (kt + 1) * 64);
        bf16x8 af[4][2], bf[2][2];
        #pragma unroll
        for (int mt = 0; mt < 4; mt++) {
            const int row = wr + mt * 16 + m16;
            #pragma unroll
            for (int kk = 0; kk < 2; kk++)
                af[mt][kk] = *(const bf16x8*)&sA[cur][row * 64 + ((kk * 4 + quad) ^ (m16 & 7)) * 8];
        }
        #pragma unroll
        for (int nt2 = 0; nt2 < 2; nt2++) {
            const int row = wc + nt2 * 16 + m16;
            #pragma unroll
            for (int kk = 0; kk < 2; kk++)
                bf[nt2][kk] = *(const bf16x8*)&sB[cur][row * 64 + ((kk * 4 + quad) ^ (m16 & 7)) * 8];
        }
        #pragma unroll
        for (int kk = 0; kk < 2; kk++)
            #pragma unroll
            for (int mt = 0; mt < 4; mt++)
                #pragma unroll
                for (int nt2 = 0; nt2 < 2; nt2++)
                    acc[mt][nt2] = __builtin_amdgcn_mfma_f32_16x16x32_bf16(af[mt][kk], bf[nt2][kk], acc[mt][nt2], 0, 0, 0);
        cur ^= 1;
    }

    #pragma unroll
    for (int mt = 0; mt < 4; mt++) {
        const int row = tm + wr + mt * 16 + quad * 4;
        #pragma unroll
        for (int nt2 = 0; nt2 < 2; nt2++) {
            const int col = tn + wc + nt2 * 16 + m16;
            #pragma unroll
            for (int r = 0; r < 4; r++) {
                if (OUT_F32)
                    ((float*)Cout)[(size_t)(row + r) * ldo + col] = acc[mt][nt2][r];
                else
                    ((ushort_t*)Cout)[(size_t)(row + r) * ldo + col] = f2bf(acc[mt][nt2][r]);
            }
        }
    }
}

// ---------------------------------------------------------------------------
// RoPE, lane-per-element: one wave per 64-elem head slice, 1 shuffle/lane.
// Q pre-scaled by 0.125*log2(e) (exp2-domain attention scores).
// HW trig: angle in revolutions, fract + v_sin/v_cos (error ~2e-4).
// ---------------------------------------------------------------------------
#define QSCALE 0.18033688011112042f   // 0.125 * log2(e)
__global__ __launch_bounds__(256) void rope_kernel(ushort_t* qkv, ushort_t* __restrict__ Kr)
{
    const int gid = blockIdx.x * 256 + threadIdx.x;
    const int lane = gid & 63;
    const int idx = gid >> 6;              // slice index
    const int s = idx / 40;
    const int hh = idx - s * 40;

    const ushort_t* src;
    ushort_t* dst;
    const bool isq = (hh < 32);
    if (isq) {
        dst = qkv + (size_t)s * QKV_LD + hh * 64;
        src = dst;
    } else {
        src = qkv + (size_t)s * QKV_LD + 2048 + (hh - 32) * 64;
        dst = Kr + ((size_t)(hh - 32) * SEQ + s) * 64;
    }

    const float e = bf2f(src[lane]);
    const int i = lane & 31;
    // freq/(2*pi) = exp2(-i*log2(10000)/32) * (1/2pi)
    const float freq_rev = __builtin_amdgcn_exp2f(-(float)i * 0.4152410118609203f)
                           * 0.15915494309189535f;
    float fr = (float)s * freq_rev;
    fr = fr - floorf(fr);                  // v_fract range reduction
    const float cv = __builtin_amdgcn_cosf(fr);   // cos(fr * 2pi)
    const float sv = __builtin_amdgcn_sinf(fr);   // sin(fr * 2pi)
    const int partner = (lane < 32) ? (2 * lane + 1) : (2 * (lane - 32));
    const float y = __shfl(e, partner, 64);
    float out = (lane < 32) ? (e * cv - y * sv) : (e * cv + y * sv);
    if (isq) out *= QSCALE;
    dst[lane] = f2bf(out);
}

// ---------------------------------------------------------------------------
// V transpose (tiled through LDS): Vt[kvh][d][s] = qkv[s][2560+kvh*64+d]
// ---------------------------------------------------------------------------
__global__ __launch_bounds__(256) void vtrans_kernel(
    const ushort_t* __restrict__ qkv, ushort_t* __restrict__ Vt)
{
    __shared__ __align__(16) ushort_t tile[64][72];
    const int kvh = blockIdx.x & 7;
    const int s0 = (blockIdx.x >> 3) * 64;
    const int t = threadIdx.x;
    {
        const int sr = t >> 3;
        const int d8 = (t & 7) * 8;
        #pragma unroll
        for (int i = 0; i < 2; i++) {
            const int s = sr + i * 32;
            ushort_t tmp[8];
            *(uint4*)tmp = *(const uint4*)(qkv + (size_t)(s0 + s) * QKV_LD + 2560 + kvh * 64 + d8);
            #pragma unroll
            for (int j = 0; j < 8; j++) tile[d8 + j][s] = tmp[j];
        }
    }
    __syncthreads();
    {
        const int dr = t >> 3;
        const int s8 = (t & 7) * 8;
        #pragma unroll
        for (int i = 0; i < 2; i++) {
            const int d = dr + i * 32;
            *(uint4*)(Vt + ((size_t)kvh * 64 + d) * SEQ + s0 + s8) = *(const uint4*)&tile[d][s8];
        }
    }
}

// ---------------------------------------------------------------------------
// Flash attention (R9 verbatim — proven 69.5 us; R12's 4-wave restructure
// couldn't change waves/SIMD (2048 wave-jobs either way) and regressed via
// VGPR 136 + lost pairing).
// Block = 512 threads (8 waves), no barriers. Waves 0-3: band 15-p (128 q),
// waves 4-7: band p -> per-CU work exactly uniform, grid 256 = 1 block/CU.
// XCD-aware: kvh = blockIdx & 7 -> one kv-head per XCD L2 (FETCH halved).
// Zero LDS; in-register softmax (exp2 domain, deferred max THR=8);
// P^T via cvt_pk + permlane swaps; explicit unroll-by-2 K double-buffer.
// ---------------------------------------------------------------------------
#define MFMA16(A, B, C) __builtin_amdgcn_mfma_f32_16x16x32_bf16(A, B, C, 0, 0, 0)

#define LOADK(KF, KB) do { \
    _Pragma("unroll") \
    for (int _k = 0; _k < 4; _k++) { \
        const ushort_t* _kp = Krh + (size_t)((KB) + _k * 16 + m16) * 64 + quad * 8; \
        KF[_k][0] = *(const bf16x8*)_kp; \
        KF[_k][1] = *(const bf16x8*)(_kp + 32); \
    } \
} while (0)

#define LOADV(VF, KB) do { \
    _Pragma("unroll") \
    for (int _n = 0; _n < 4; _n++) { \
        const ushort_t* _vp = Vth + (size_t)(_n * 16 + m16) * SEQ + (KB) + quad * 8; \
        VF[_n][0] = *(const bf16x8*)_vp; \
        VF[_n][1] = *(const bf16x8*)(_vp + 32); \
    } \
} while (0)

#define QKT(SC, KF, QA) do { \
    _Pragma("unroll") \
    for (int _k = 0; _k < 4; _k++) { \
        SC[_k] = MFMA16(KF[_k][0], qf[QA][0], SC[_k]); \
        SC[_k] = MFMA16(KF[_k][1], qf[QA][1], SC[_k]); \
    } \
} while (0)

#define SMPV(SC, QA, DOMASK, KBASE, VF) do { \
    float s_[16]; \
    _Pragma("unroll") \
    for (int _k = 0; _k < 4; _k++) { \
        _Pragma("unroll") \
        for (int _r = 0; _r < 4; _r++) { \
            float _v = SC[_k][_r]; \
            if ((DOMASK) && ((KBASE) + _k * 16 + quad * 4 + _r > qi[QA])) _v = -1e30f; \
            s_[_k * 4 + _r] = _v; \
        } \
    } \
    float _x0 = fmaxf(s_[0], s_[1]),   _x1 = fmaxf(s_[2], s_[3]); \
    float _x2 = fmaxf(s_[4], s_[5]),   _x3 = fmaxf(s_[6], s_[7]); \
    float _x4 = fmaxf(s_[8], s_[9]),   _x5 = fmaxf(s_[10], s_[11]); \
    float _x6 = fmaxf(s_[12], s_[13]), _x7 = fmaxf(s_[14], s_[15]); \
    float _rmax = fmaxf(fmaxf(fmaxf(_x0, _x1), fmaxf(_x2, _x3)), \
                        fmaxf(fmaxf(_x4, _x5), fmaxf(_x6, _x7))); \
    _rmax = wave_max(_rmax); \
    if (_rmax > m_run[QA] + 8.f) { \
        const float _mnew = fmaxf(m_run[QA], _rmax); \
        const float _alpha = __builtin_amdgcn_exp2f(m_run[QA] - _mnew); \
        m_run[QA] = _mnew; \
        l_run[QA] *= _alpha; \
        _Pragma("unroll") \
        for (int _n = 0; _n < 4; _n++) { \
            _Pragma("unroll") \
            for (int _r = 0; _r < 4; _r++) oacc[QA][_n][_r] *= _alpha; \
        } \
    } \
    const float _m = m_run[QA]; \
    _Pragma("unroll") \
    for (int _i = 0; _i < 16; _i++) s_[_i] = __builtin_amdgcn_exp2f(s_[_i] - _m); \
    float _y0 = s_[0] + s_[1],   _y1 = s_[2] + s_[3]; \
    float _y2 = s_[4] + s_[5],   _y3 = s_[6] + s_[7]; \
    float _y4 = s_[8] + s_[9],   _y5 = s_[10] + s_[11]; \
    float _y6 = s_[12] + s_[13], _y7 = s_[14] + s_[15]; \
    float _ps = ((_y0 + _y1) + (_y2 + _y3)) + ((_y4 + _y5) + (_y6 + _y7)); \
    l_run[QA] += wave_sum(_ps); \
    unsigned int _u00 = cvt_pk_bf16(s_[0],  s_[1]),  _u01 = cvt_pk_bf16(s_[2],  s_[3]); \
    unsigned int _u10 = cvt_pk_bf16(s_[4],  s_[5]),  _u11 = cvt_pk_bf16(s_[6],  s_[7]); \
    unsigned int _u20 = cvt_pk_bf16(s_[8],  s_[9]),  _u21 = cvt_pk_bf16(s_[10], s_[11]); \
    unsigned int _u30 = cvt_pk_bf16(s_[12], s_[13]), _u31 = cvt_pk_bf16(s_[14], s_[15]); \
    pswap32(_u00, _u10); pswap16(_u00, _u10); \
    pswap32(_u01, _u11); pswap16(_u01, _u11); \
    pswap32(_u20, _u30); pswap16(_u20, _u30); \
    pswap32(_u21, _u31); pswap16(_u21, _u31); \
    union { unsigned int w[4]; bf16x8 v; } _P0, _P1; \
    _P0.w[0] = _u00; _P0.w[1] = _u01; _P0.w[2] = _u10; _P0.w[3] = _u11; \
    _P1.w[0] = _u20; _P1.w[1] = _u21; _P1.w[2] = _u30; _P1.w[3] = _u31; \
    __builtin_amdgcn_s_setprio(1); \
    _Pragma("unroll") \
    for (int _n = 0; _n < 4; _n++) { \
        oacc[QA][_n] = MFMA16(VF[_n][0], _P0.v, oacc[QA][_n]); \
        oacc[QA][_n] = MFMA16(VF[_n][1], _P1.v, oacc[QA][_n]); \
    } \
    __builtin_amdgcn_s_setprio(0); \
} while (0)

__global__ __launch_bounds__(512, 2) void attn_kernel(
    ushort_t* qkv, const ushort_t* __restrict__ Kr, const ushort_t* __restrict__ Vt)
{
    const int t = threadIdx.x, wave = t >> 6, lane = t & 63;
    const int m16 = lane & 15, quad = lane >> 4;
    // XCD-aware decode: kvh == blockIdx%8 -> one kv-head per XCD L2.
    const int b = blockIdx.x;
    const int kvh = b & 7;
    const int h = kvh * 4 + ((b >> 3) & 3);
    const int p = b >> 5;                      // pair index 0..7
    const int grp = wave >> 2;                 // 0: heavy band, 1: light band
    const int w4 = wave & 3;
    const int band = grp ? p : 15 - p;         // 128-query band

    const ushort_t* Krh = Kr + (size_t)kvh * SEQ * 64;   // [s][d]
    const ushort_t* Vth = Vt + (size_t)kvh * 64 * SEQ;   // [d][s]

    const int nkt = band * 2 + 2;              // always even

    // Two 16-query strips per wave: qa=0 -> lower 64 of band, qa=1 -> upper.
    int qi[2];
    bf16x8 qf[2][2];
    #pragma unroll
    for (int qa = 0; qa < 2; qa++) {
        qi[qa] = band * 128 + (w4 + qa * 4) * 16 + m16;
        const ushort_t* qp = qkv + (size_t)qi[qa] * QKV_LD + h * 64 + quad * 8;
        qf[qa][0] = *(const bf16x8*)qp;
        qf[qa][1] = *(const bf16x8*)(qp + 32);
    }

    f32x4 oacc[2][4] = {};                  // O^T: col=q(m16), row=d
    float m_run[2] = { -1e30f, -1e30f };
    float l_run[2] = { 0.f, 0.f };

    bf16x8 kfA[4][2], kfB[4][2], vf[4][2];
    LOADK(kfA, 0);                          // prologue (pays latency once)

    for (int kt = 0; kt < nkt; kt += 2) {
        const bool lastpair = (kt == nkt - 2);
        const int kb0 = kt * 64, kb1 = kb0 + 64;

        // ---- even tile kt (buffers kfA) ----
        f32x4 scA0[4] = {}, scA1[4] = {};
        __builtin_amdgcn_s_setprio(1);
        QKT(scA0, kfA, 0);
        QKT(scA1, kfA, 1);
        __builtin_amdgcn_s_setprio(0);
        LOADV(vf, kb0);                     // consumed after softmax (~230cy)
        LOADK(kfB, kb1);                    // consumed next phase (~600cy)
        SMPV(scA0, 0, lastpair, kb0, vf);   // qa0 masks at tile nkt-2
        SMPV(scA1, 1, false,    kb0, vf);

        // ---- odd tile kt+1 (buffers kfB) ----
        if (!lastpair) {
            f32x4 scB0[4] = {}, scB1[4] = {};
            __builtin_amdgcn_s_setprio(1);
            QKT(scB0, kfB, 0);
            QKT(scB1, kfB, 1);
            __builtin_amdgcn_s_setprio(0);
            LOADV(vf, kb1);
            LOADK(kfA, kb1 + 64);
            SMPV(scB0, 0, false, kb1, vf);
            SMPV(scB1, 1, false, kb1, vf);
        } else {
            // final tile: fully masked for qa0 (skip); qa1 masked
            f32x4 scB1[4] = {};
            __builtin_amdgcn_s_setprio(1);
            QKT(scB1, kfB, 1);
            __builtin_amdgcn_s_setprio(0);
            LOADV(vf, kb1);
            SMPV(scB1, 1, true, kb1, vf);
        }
    }

    // ---- epilogue: O[q][h*64+d] = O^T/l ----
    #pragma unroll
    for (int qa = 0; qa < 2; qa++) {
        const float rl = 1.f / l_run[qa];
        #pragma unroll
        for (int nt = 0; nt < 4; nt++) {
            ushort_t pk[4];
            #pragma unroll
            for (int r = 0; r < 4; r++) pk[r] = f2bf(oacc[qa][nt][r] * rl);
            *(uint2*)&qkv[(size_t)qi[qa] * QKV_LD + h * 64 + nt * 16 + quad * 4] = *(uint2*)pk;
        }
    }
}

// ---------------------------------------------------------------------------
extern "C" void kernel_launch(void* const* d_in, const int* in_sizes, int n_in,
                              void* d_out, int out_size, void* d_ws, size_t ws_size,
                              hipStream_t stream)
{
    const float* x  = (const float*)d_in[0];
    // d_in[1] = mask (int32) — causal, handled analytically
    const float* wq = (const float*)d_in[2];
    const float* wk = (const float*)d_in[3];
    const float* wv = (const float*)d_in[4];
    const float* wo = (const float*)d_in[5];

    ushort_t* WT  = (ushort_t*)d_ws;                    // [3072][2048] bf16
    ushort_t* xb  = WT + (size_t)3072 * 2048;           // [2048][2048] bf16
    ushort_t* woT = xb;                                 // alias: xb dead after QKV GEMM
    ushort_t* qkv = xb + (size_t)2048 * 2048;           // [2048][3072] bf16
    ushort_t* Kr  = qkv + (size_t)SEQ * QKV_LD;         // [8][2048][64]
    ushort_t* Vt  = Kr + (size_t)NKV * SEQ * HD;        // [8][64][2048]

    dim3 blk(256);

    convert_kernel<<<(DIM * SEQ) / 1024, blk, 0, stream>>>(x, xb);
    transpose_kernel<<<dim3(32, 32), blk, 0, stream>>>(wq, WT, 2048);
    transpose_kernel<<<dim3(8, 32),  blk, 0, stream>>>(wk, WT + (size_t)2048 * 2048, 512);
    transpose_kernel<<<dim3(8, 32),  blk, 0, stream>>>(wv, WT + (size_t)2560 * 2048, 512);

    // Fused QKV projection: [2048,2048] x [2048,3072] -> qkv (128x64, BK=64, dbuf)
    gemm_kernel<0><<<dim3(QKV_LD / 64, SEQ / 128), blk, 0, stream>>>(xb, WT, qkv, DIM, DIM, QKV_LD);

    // wo transpose (reuses xb region — must follow the QKV GEMM)
    transpose_kernel<<<dim3(32, 32), blk, 0, stream>>>(wo, woT, 2048);

    // RoPE: SEQ*40 slices, one wave each (Q pre-scaled to exp2 domain)
    rope_kernel<<<(SEQ * 40 * 64) / 256, blk, 0, stream>>>(qkv, Kr);
    vtrans_kernel<<<NKV * (SEQ / 64), blk, 0, stream>>>(qkv, Vt);

    // Attention: 8 band-pairs x 32 heads, XCD-swizzled, 512-thread blocks
    attn_kernel<<<8 * NH, dim3(512), 0, stream>>>(qkv, Kr, Vt);

    // Output projection -> d_out fp32 (128x64, BK=64, dbuf, 512 blocks = 2/CU)
    gemm_kernel<1><<<dim3(DIM / 64, SEQ / 128), blk, 0, stream>>>(qkv, woT, d_out, DIM, QKV_LD, DIM);
}